// Round 4
// baseline (220.336 us; speedup 1.0000x reference)
//
#include <hip/hip_runtime.h>
#include <stdint.h>

// Problem constants (B, N, D, QM, QP, NP, T) = (16, 900, 256, 4, 4, 6, 4)
// Storage model (established R0-R3): float arrays are bf16-ROUNDED values in
// FLOAT32 containers; output buffer is FLOAT32 (out_size floats). Bool/int
// input storage is detected at runtime (i32 / u8 / bf16 / f32).
namespace {
constexpr int Bn = 16, Nn = 900, Dn = 256, QMn = 4, QPn = 4, NPn = 6, Tn = 4;

constexpr int SZ_MQ  = Bn * QMn * Nn * Dn;        // 14,745,600
constexpr int SZ_PQ  = Bn * QPn * NPn * Dn;       //     98,304
constexpr int SZ_EQ  = Bn * QPn * Dn;             //     16,384
constexpr int SZ_PER = Bn * QMn;                  //         64
constexpr int SZ_MM  = Bn * (Tn - 1) * Nn;        //     43,200
constexpr int SZ_ME  = Bn * (Tn - 1) * Nn * Dn;   // 11,059,200
constexpr int SZ_PM  = Bn * (Tn - 1);             //         48
constexpr int SZ_PE  = Bn * (Tn - 1) * Dn;        //     12,288

constexpr int OFF_MQ  = 0;
constexpr int OFF_PQ  = OFF_MQ + SZ_MQ;
constexpr int OFF_EQ  = OFF_PQ + SZ_PQ;
constexpr int OFF_PER = OFF_EQ + SZ_EQ;
constexpr int OFF_MM  = OFF_PER + SZ_PER;
constexpr int OFF_ME  = OFF_MM + SZ_MM;
constexpr int OFF_PM  = OFF_ME + SZ_ME;
constexpr int OFF_PE  = OFF_PM + SZ_PM;
constexpr int TOTAL   = OFF_PE + SZ_PE;           // 25,975,088 (divisible by 8)
}  // namespace

using u16 = unsigned short;

__device__ __forceinline__ float bits_to_f(unsigned u) {
    return __builtin_bit_cast(float, u);
}

// ---------------- runtime storage-mode detection ----------------
// Float arrays: 0 = f32 container, 1 = bf16 container.
__device__ int detect_float_mode(const void* p) {
    const unsigned* w = (const unsigned*)p;
    int cnt = 0;
#pragma unroll
    for (int i = 0; i < 32; ++i) {
        unsigned ex = (w[i] >> 7) & 0xFFu;   // bf16 exponent field of low halfword
        cnt += (ex >= 120u && ex <= 133u) ? 1 : 0;
    }
    return (cnt >= 16) ? 1 : 0;
}

enum { BM_I32 = 0, BM_U8 = 1, BM_BF16 = 2, BM_F32 = 3 };
__device__ int detect_bool_mode(const void* p) {
    const unsigned* w = (const unsigned*)p;
    unsigned orw = 0, or_even = 0;
    bool hw_ok = true, u8_ok = true;
#pragma unroll
    for (int i = 0; i < 64; ++i) {
        unsigned x = w[i];
        orw |= x;
        unsigned lo = x & 0xFFFFu, hi = x >> 16;
        hw_ok = hw_ok && (lo == 0u || lo == 0x3F80u) && (hi == 0u || hi == 0x3F80u);
        or_even |= lo;
        u8_ok = u8_ok && ((x & 0xFEFEFEFEu) == 0u);
    }
    if (orw <= 1u) return BM_I32;
    if (hw_ok)     return (or_even == 0u) ? BM_F32 : BM_BF16;
    if (u8_ok)     return BM_U8;
    return BM_I32;
}

__device__ __forceinline__ bool get_bool(const void* p, int i, int m) {
    if (m == BM_I32) return ((const int*)p)[i] != 0;
    if (m == BM_U8)  return ((const unsigned char*)p)[i] != 0;
    if (m == BM_BF16) return ((const u16*)p)[i] != 0;
    return ((const unsigned*)p)[i] != 0;     // F32: 0x3F800000 / 0
}

// period (values {0,1,2,3}): 0 = i32, 1 = bf16, 2 = f32.
__device__ int detect_period_mode(const void* p) {
    const unsigned* w = (const unsigned*)p;
    unsigned orw = 0, or_even = 0;
    bool hw_ok = true;
#pragma unroll
    for (int i = 0; i < 16; ++i) {
        unsigned x = w[i];
        orw |= x;
        unsigned lo = x & 0xFFFFu, hi = x >> 16;
        bool lo_ok = (lo == 0u || lo == 0x3F80u || lo == 0x4000u || lo == 0x4040u);
        bool hi_ok = (hi == 0u || hi == 0x3F80u || hi == 0x4000u || hi == 0x4040u);
        hw_ok = hw_ok && lo_ok && hi_ok;
        or_even |= lo;
    }
    if (orw <= 3u) return 0;
    if (hw_ok && or_even == 0u) return 2;
    return 1;
}

__device__ __forceinline__ float get_period_f(const void* p, int i, int m) {
    if (m == 0) return (float)((const int*)p)[i];
    if (m == 1) return bits_to_f((unsigned)((const u16*)p)[i] << 16);
    return ((const float*)p)[i];
}

// Load 8 contiguous float-typed elements starting at element e -> two float4.
__device__ __forceinline__ void load8f(const void* base, int e, int fm,
                                       float4& A, float4& B) {
    if (fm == 0) {
        const float* f = (const float*)base + e;
        A = reinterpret_cast<const float4*>(f)[0];
        B = reinterpret_cast<const float4*>(f)[1];
    } else {
        const int4 r = *reinterpret_cast<const int4*>((const u16*)base + e);
        unsigned x;
        x = (unsigned)r.x; A.x = bits_to_f(x << 16); A.y = bits_to_f(x & 0xFFFF0000u);
        x = (unsigned)r.y; A.z = bits_to_f(x << 16); A.w = bits_to_f(x & 0xFFFF0000u);
        x = (unsigned)r.z; B.x = bits_to_f(x << 16); B.y = bits_to_f(x & 0xFFFF0000u);
        x = (unsigned)r.w; B.z = bits_to_f(x << 16); B.w = bits_to_f(x & 0xFFFF0000u);
    }
}

__global__ __launch_bounds__(256) void state_queue_kernel(
    const void* __restrict__ motion_query,        // (B,N,D) float-typed
    const void* __restrict__ plan_query,          // (B,NP,D)
    const void* __restrict__ ego_status_feature,  // (B,D)
    const void* __restrict__ motion_queue,        // (B,QM,N,D)
    const void* __restrict__ plan_queue,          // (B,QP,NP,D)
    const void* __restrict__ ego_status_queue,    // (B,QP,D)
    const void* __restrict__ period,              // (B,QM) int-typed
    const void* __restrict__ mask,                // (B,) bool-typed
    const void* __restrict__ temp_anchor,         // (B,N,T,D)
    const void* __restrict__ temp_mask,           // (B,N,T) bool-typed
    const void* __restrict__ ego_anchor,          // (B,1,T,D)
    const void* __restrict__ ego_mask,            // (B,1,T) bool-typed
    float* __restrict__ out)
{
    __shared__ int s_modes[3];
    if (threadIdx.x == 0) {
        s_modes[0] = detect_float_mode(motion_query);
        s_modes[1] = detect_bool_mode(temp_mask);
        s_modes[2] = detect_period_mode(period);
    }
    __syncthreads();
    const int fm = s_modes[0];
    const int bm = s_modes[1];
    const int pmode = s_modes[2];

    const int pack = blockIdx.x * blockDim.x + threadIdx.x;
    const int idx = pack * 8;
    if (idx >= TOTAL) return;

    float4 A, B;

    if (idx < OFF_PQ) {
        // ---- mq: out[b,q,n,d] = reset ? motion_query[b,n,d] : motion_queue[b,q,n,d]
        const int e = idx - OFF_MQ;
        const int d = e & (Dn - 1);
        const unsigned row = (unsigned)(e >> 8);     // (b*QM+q)*N + n
        const unsigned bq = row / (unsigned)Nn;
        const unsigned n = row - bq * (unsigned)Nn;
        const unsigned b = bq >> 2;
        const bool reset = !get_bool(mask, (int)b, bm);
        if (reset) load8f(motion_query, (((int)b * Nn + (int)n) << 8) + d, fm, A, B);
        else       load8f(motion_queue, e, fm, A, B);
    } else if (idx < OFF_EQ) {
        // ---- pq
        const int e = idx - OFF_PQ;
        const int d = e & (Dn - 1);
        const unsigned row = (unsigned)(e >> 8);     // (b*QP+q)*NP + p
        const unsigned b = row / (unsigned)(QPn * NPn);
        const unsigned rem = row - b * (unsigned)(QPn * NPn);
        const unsigned q = rem / (unsigned)NPn;
        const unsigned p = rem - q * (unsigned)NPn;
        const bool reset = !get_bool(mask, (int)b, bm);
        if (reset) load8f(plan_query, (((int)b * NPn + (int)p) << 8) + d, fm, A, B);
        else       load8f(plan_queue, e, fm, A, B);
    } else if (idx < OFF_PER) {
        // ---- eq
        const int e = idx - OFF_EQ;
        const int d = e & (Dn - 1);
        const int row = e >> 8;                      // b*QP + q
        const int b = row >> 2;
        const bool reset = !get_bool(mask, b, bm);
        if (reset) load8f(ego_status_feature, (b << 8) + d, fm, A, B);
        else       load8f(ego_status_queue, e, fm, A, B);
    } else if (idx < OFF_MM) {
        // ---- per: out[b,q] = reset ? 0 : period[b,q]
        const int e = idx - OFF_PER;
        float h[8];
#pragma unroll
        for (int k = 0; k < 8; ++k) {
            const int g = e + k;
            const int b = g >> 2;
            const bool reset = !get_bool(mask, b, bm);
            h[k] = reset ? 0.0f : get_period_f(period, g, pmode);
        }
        A = make_float4(h[0], h[1], h[2], h[3]);
        B = make_float4(h[4], h[5], h[6], h[7]);
    } else if (idx < OFF_ME) {
        // ---- mm (transposed): out[b,t,n] = temp_mask[b,n,t], t < T-1
        const int e = idx - OFF_MM;
        float h[8];
#pragma unroll
        for (int k = 0; k < 8; ++k) {
            const unsigned g = (unsigned)(e + k);
            const unsigned b = g / (unsigned)((Tn - 1) * Nn);
            const unsigned rem = g - b * (unsigned)((Tn - 1) * Nn);
            const unsigned t = rem / (unsigned)Nn;
            const unsigned n = rem - t * (unsigned)Nn;
            h[k] = get_bool(temp_mask, ((int)b * Nn + (int)n) * Tn + (int)t, bm)
                       ? 1.0f : 0.0f;
        }
        A = make_float4(h[0], h[1], h[2], h[3]);
        B = make_float4(h[4], h[5], h[6], h[7]);
    } else if (idx < OFF_PM) {
        // ---- me (transposed): out[b,t,n,d] = temp_anchor[b,n,t,d], t < T-1
        const int e = idx - OFF_ME;
        const int d = e & (Dn - 1);
        const unsigned row = (unsigned)(e >> 8);     // b*(T-1)*N + t*N + n
        const unsigned b = row / (unsigned)((Tn - 1) * Nn);
        const unsigned rem = row - b * (unsigned)((Tn - 1) * Nn);
        const unsigned t = rem / (unsigned)Nn;
        const unsigned n = rem - t * (unsigned)Nn;
        load8f(temp_anchor, ((((int)b * Nn + (int)n) * Tn + (int)t) << 8) + d, fm, A, B);
    } else if (idx < OFF_PE) {
        // ---- pm (transposed, unmodified): out[b,t,0] = ego_mask[b,0,t]
        const int e = idx - OFF_PM;
        float h[8];
#pragma unroll
        for (int k = 0; k < 8; ++k) {
            const unsigned g = (unsigned)(e + k);
            const unsigned b = g / (unsigned)(Tn - 1);
            const unsigned t = g - b * (unsigned)(Tn - 1);
            h[k] = get_bool(ego_mask, (int)b * Tn + (int)t, bm) ? 1.0f : 0.0f;
        }
        A = make_float4(h[0], h[1], h[2], h[3]);
        B = make_float4(h[4], h[5], h[6], h[7]);
    } else {
        // ---- pe (transposed + overwrite): out[b,t,0,d]
        const int e = idx - OFF_PE;
        const int d = e & (Dn - 1);
        const unsigned row = (unsigned)(e >> 8);     // b*(T-1) + t
        const unsigned b = row / (unsigned)(Tn - 1);
        const unsigned t = row - b * (unsigned)(Tn - 1);

        bool any_flag = false;
#pragma unroll
        for (int bb = 0; bb < Bn; ++bb) {
            any_flag = any_flag || get_bool(ego_mask, bb * Tn + 0, bm)
                                || get_bool(ego_mask, bb * Tn + 1, bm)
                                || get_bool(ego_mask, bb * Tn + 2, bm);
        }

        const bool p0 = get_bool(ego_mask, (int)b * Tn + 0, bm);
        const bool p1 = get_bool(ego_mask, (int)b * Tn + 1, bm);
        const bool p2 = get_bool(ego_mask, (int)b * Tn + 2, bm);
        const bool all_true = p0 && p1 && p2;
        const int first_false = (!p0) ? 0 : ((!p1) ? 1 : ((!p2) ? 2 : 0));

        const bool overwrite = all_true || ((int)t < first_false);
        int src_t = (int)t;
        if (any_flag && overwrite) src_t = all_true ? (Tn - 1) : first_false;

        load8f(ego_anchor, (((int)b * Tn + src_t) << 8) + d, fm, A, B);
    }

    reinterpret_cast<float4*>(out + idx)[0] = A;
    reinterpret_cast<float4*>(out + idx)[1] = B;
}

extern "C" void kernel_launch(void* const* d_in, const int* in_sizes, int n_in,
                              void* d_out, int out_size, void* d_ws, size_t ws_size,
                              hipStream_t stream) {
    float* out = (float*)d_out;
    const int packs = TOTAL / 8;               // 3,246,886
    const int threads = 256;
    const int blocks = (packs + threads - 1) / threads;
    state_queue_kernel<<<blocks, threads, 0, stream>>>(
        d_in[0], d_in[1], d_in[2], d_in[3], d_in[4], d_in[5], d_in[6], d_in[7],
        d_in[8], d_in[9], d_in[10], d_in[11], out);
}